// Round 2
// baseline (2249.942 us; speedup 1.0000x reference)
//
#include <hip/hip_runtime.h>
#include <cstddef>

#define Bx 2
#define Tn 4096
#define Hh 8

typedef unsigned short u16;
typedef unsigned int u32;

__device__ __forceinline__ float bf2f(u16 u) {
  u32 x = ((u32)u) << 16;
  return __uint_as_float(x);
}
__device__ __forceinline__ u16 f2bf(float f) {
  u32 x = __float_as_uint(f);
  u32 lsb = (x >> 16) & 1;
  x += 0x7fffu + lsb;
  return (u16)(x >> 16);
}
__device__ __forceinline__ u32 pack2(float a, float b) {
  return (u32)f2bf(a) | ((u32)f2bf(b) << 16);
}

// ---------------------------------------------------------------------------
// qkvz GEMM (8192x4096x1024 fp32) with split epilogue -> bf16 mixed & z.
// 128x128 tile, BK=8, 256 threads, 8x8 micro-tile.
// ---------------------------------------------------------------------------
__global__ __launch_bounds__(256) void gemm_qkvz(const float* __restrict__ A,
                                                 const float* __restrict__ Bw,
                                                 u16* __restrict__ mixed,
                                                 u16* __restrict__ zb) {
  __shared__ float As[8][128];
  __shared__ float Bs[8][128];
  const int K = 1024, N = 4096;
  int bm = blockIdx.y, bn = blockIdx.x;
  int tid = threadIdx.x;
  int tx = tid & 15, ty = tid >> 4;
  float acc[8][8] = {};
  int arow = tid >> 1, ac4 = (tid & 1) * 4;
  int brow = tid >> 5, bc4 = (tid & 31) * 4;
  const float* Aptr = A + (size_t)(bm * 128 + arow) * K + ac4;
  const float* Bptr = Bw + (size_t)brow * N + bn * 128 + bc4;

  for (int kk = 0; kk < K; kk += 8) {
    float4 a4 = *(const float4*)(Aptr + kk);
    float4 b4 = *(const float4*)(Bptr + (size_t)kk * N);
    As[ac4 + 0][arow] = a4.x;
    As[ac4 + 1][arow] = a4.y;
    As[ac4 + 2][arow] = a4.z;
    As[ac4 + 3][arow] = a4.w;
    *(float4*)&Bs[brow][bc4] = b4;
    __syncthreads();
#pragma unroll
    for (int k = 0; k < 8; k++) {
      float a0[8], b0[8];
      *(float4*)&a0[0] = *(float4*)&As[k][ty * 8];
      *(float4*)&a0[4] = *(float4*)&As[k][ty * 8 + 4];
      *(float4*)&b0[0] = *(float4*)&Bs[k][tx * 8];
      *(float4*)&b0[4] = *(float4*)&Bs[k][tx * 8 + 4];
#pragma unroll
      for (int i = 0; i < 8; i++)
#pragma unroll
        for (int j = 0; j < 8; j++) acc[i][j] += a0[i] * b0[j];
    }
    __syncthreads();
  }

  int m0 = bm * 128 + ty * 8;
  int n0 = bn * 128;
  int h = n0 >> 9;
  int sub = (n0 >> 7) & 3;
  u16* dst;
  size_t stride;
  if (sub < 3) { dst = mixed + (size_t)(sub * 1024 + h * 128); stride = 3072; }
  else         { dst = zb + (size_t)(h * 128);                 stride = 1024; }
#pragma unroll
  for (int i = 0; i < 8; i++) {
    uint4 pv;
    pv.x = pack2(acc[i][0], acc[i][1]);
    pv.y = pack2(acc[i][2], acc[i][3]);
    pv.z = pack2(acc[i][4], acc[i][5]);
    pv.w = pack2(acc[i][6], acc[i][7]);
    *(uint4*)&dst[(size_t)(m0 + i) * stride + tx * 8] = pv;
  }
}

// ---------------------------------------------------------------------------
// Output GEMM (8192x1024x1024 fp32), plain f32 store.
// ---------------------------------------------------------------------------
__global__ __launch_bounds__(256) void gemm_out(const float* __restrict__ A,
                                                const float* __restrict__ Bw,
                                                float* __restrict__ O) {
  __shared__ float As[8][128];
  __shared__ float Bs[8][128];
  const int K = 1024, N = 1024;
  int bm = blockIdx.y, bn = blockIdx.x;
  int tid = threadIdx.x;
  int tx = tid & 15, ty = tid >> 4;
  float acc[8][8] = {};
  int arow = tid >> 1, ac4 = (tid & 1) * 4;
  int brow = tid >> 5, bc4 = (tid & 31) * 4;
  const float* Aptr = A + (size_t)(bm * 128 + arow) * K + ac4;
  const float* Bptr = Bw + (size_t)brow * N + bn * 128 + bc4;

  for (int kk = 0; kk < K; kk += 8) {
    float4 a4 = *(const float4*)(Aptr + kk);
    float4 b4 = *(const float4*)(Bptr + (size_t)kk * N);
    As[ac4 + 0][arow] = a4.x;
    As[ac4 + 1][arow] = a4.y;
    As[ac4 + 2][arow] = a4.z;
    As[ac4 + 3][arow] = a4.w;
    *(float4*)&Bs[brow][bc4] = b4;
    __syncthreads();
#pragma unroll
    for (int k = 0; k < 8; k++) {
      float a0[8], b0[8];
      *(float4*)&a0[0] = *(float4*)&As[k][ty * 8];
      *(float4*)&a0[4] = *(float4*)&As[k][ty * 8 + 4];
      *(float4*)&b0[0] = *(float4*)&Bs[k][tx * 8];
      *(float4*)&b0[4] = *(float4*)&Bs[k][tx * 8 + 4];
#pragma unroll
      for (int i = 0; i < 8; i++)
#pragma unroll
        for (int j = 0; j < 8; j++) acc[i][j] += a0[i] * b0[j];
    }
    __syncthreads();
  }

  int m0 = bm * 128 + ty * 8;
  int n0 = bn * 128;
#pragma unroll
  for (int i = 0; i < 8; i++) {
    float4 v0 = make_float4(acc[i][0], acc[i][1], acc[i][2], acc[i][3]);
    float4 v1 = make_float4(acc[i][4], acc[i][5], acc[i][6], acc[i][7]);
    size_t rb = (size_t)(m0 + i) * N + n0 + tx * 8;
    *(float4*)&O[rb] = v0;
    *(float4*)&O[rb + 4] = v1;
  }
}

// ---------------------------------------------------------------------------
// ba = x @ W_ba then beta = sigmoid(b), g = -exp(A)*softplus(a+dt)
// ---------------------------------------------------------------------------
__global__ __launch_bounds__(128) void ba_kernel(const float* __restrict__ x,
                                                 const float* __restrict__ Wba,
                                                 const float* __restrict__ dtb,
                                                 const float* __restrict__ Alog,
                                                 float* __restrict__ betab,
                                                 float* __restrict__ gb) {
  __shared__ float xs[1024];
  __shared__ float res[16];
  int row = blockIdx.x, tid = threadIdx.x;
#pragma unroll
  for (int r = 0; r < 2; r++) {
    int f4 = r * 128 + tid;
    *(float4*)&xs[f4 * 4] = *(const float4*)&x[(size_t)row * 1024 + f4 * 4];
  }
  __syncthreads();
  if (tid < 16) {
    float a = 0.f;
    for (int k2 = 0; k2 < 1024; k2++) a += xs[k2] * Wba[k2 * 16 + tid];
    res[tid] = a;
  }
  __syncthreads();
  if (tid < 8) {
    float bval = res[tid * 2], aval = res[tid * 2 + 1];
    betab[(size_t)row * 8 + tid] = 1.f / (1.f + expf(-bval));
    float spin = aval + dtb[tid];
    float sp = (spin > 20.f) ? spin : log1pf(expf(spin));
    gb[(size_t)row * 8 + tid] = -expf(Alog[tid]) * sp;
  }
}

// ---------------------------------------------------------------------------
// Per-chunk prep. One block per (chunk, bh). 256 threads.
// ---------------------------------------------------------------------------
__global__ __launch_bounds__(256) void prep(const u16* __restrict__ mixed,
                                            const float* __restrict__ cw,
                                            const float* __restrict__ gbuf,
                                            const float* __restrict__ betabuf,
                                            u16* __restrict__ qg,
                                            u16* __restrict__ kd,
                                            u16* __restrict__ vnew,
                                            u16* __restrict__ kcum,
                                            u16* __restrict__ attn,
                                            float* __restrict__ egl) {
  __shared__ float sK[64 * 132];
  __shared__ float sQ[32 * 132];  // reused as tri[64*66]
  __shared__ float gc_s[64], bet_s[64], inv_s[64], red_s[256];

  int n = blockIdx.x, bh = blockIdx.y;
  int b = bh >> 3, h = bh & 7;
  int t0 = n * 64;
  int tid = threadIdx.x;
  const int rowg0 = b * Tn + t0;
  const int rowh0 = bh * Tn + t0;

  if (tid < 64) {
    red_s[tid] = gbuf[(size_t)(rowg0 + tid) * 8 + h];
    bet_s[tid] = betabuf[(size_t)(rowg0 + tid) * 8 + h];
  }
  __syncthreads();
  if (tid == 0) {
    float s = 0.f;
    for (int i = 0; i < 64; i++) { s += red_s[i]; gc_s[i] = s; }
  }
  __syncthreads();
  float gl = gc_s[63];

  // conv k -> sK, silu
  for (int r = 0; r < 32; r++) {
    int idx = r * 256 + tid;
    int i = idx >> 7, d = idx & 127;
    int col = 1024 + h * 128 + d;
    float a = 0.f;
    int tg = t0 + i - 3;
#pragma unroll
    for (int tap = 0; tap < 4; tap++)
      if (tg + tap >= 0) a += bf2f(mixed[(size_t)(b * Tn + tg + tap) * 3072 + col]) * cw[col * 4 + tap];
    a = a / (1.f + expf(-a));
    sK[i * 132 + d] = a;
  }
  __syncthreads();
  {
    int i = tid >> 2, p = tid & 3;
    float ss = 0.f;
    for (int d = p * 32; d < p * 32 + 32; d++) { float v = sK[i * 132 + d]; ss += v * v; }
    red_s[tid] = ss;
  }
  __syncthreads();
  if (tid < 64)
    inv_s[tid] = rsqrtf(red_s[tid * 4] + red_s[tid * 4 + 1] + red_s[tid * 4 + 2] + red_s[tid * 4 + 3] + 1e-6f);
  __syncthreads();
  for (int r = 0; r < 32; r++) {
    int idx = r * 256 + tid;
    int i = idx >> 7, d = idx & 127;
    sK[i * 132 + d] *= inv_s[i];
  }
  __syncthreads();
  for (int r = 0; r < 32; r++) {
    int idx = r * 256 + tid;
    int i = idx >> 7, d = idx & 127;
    kd[(size_t)(rowh0 + i) * 128 + d] = f2bf(sK[i * 132 + d] * expf(gl - gc_s[i]));
  }

  // q halves
  for (int half = 0; half < 2; half++) {
    int i0 = half * 32;
    __syncthreads();
    for (int r = 0; r < 16; r++) {
      int idx = r * 256 + tid;
      int li = idx >> 7, d = idx & 127;
      int i = i0 + li;
      int col = h * 128 + d;
      float a = 0.f;
      int tg = t0 + i - 3;
#pragma unroll
      for (int tap = 0; tap < 4; tap++)
        if (tg + tap >= 0) a += bf2f(mixed[(size_t)(b * Tn + tg + tap) * 3072 + col]) * cw[col * 4 + tap];
      a = a / (1.f + expf(-a));
      sQ[li * 132 + d] = a;
    }
    __syncthreads();
    if (tid < 128) {
      int li = tid >> 2, p = tid & 3;
      float ss = 0.f;
      for (int d = p * 32; d < p * 32 + 32; d++) { float v = sQ[li * 132 + d]; ss += v * v; }
      red_s[tid] = ss;
    }
    __syncthreads();
    if (tid < 32)
      inv_s[tid] = rsqrtf(red_s[tid * 4] + red_s[tid * 4 + 1] + red_s[tid * 4 + 2] + red_s[tid * 4 + 3] + 1e-6f) *
                   0.08838834764831845f;
    __syncthreads();
    for (int r = 0; r < 16; r++) {
      int idx = r * 256 + tid;
      int li = idx >> 7, d = idx & 127;
      sQ[li * 132 + d] *= inv_s[li];
    }
    __syncthreads();
    for (int r = 0; r < 16; r++) {
      int idx = r * 256 + tid;
      int li = idx >> 7, d = idx & 127;
      int i = i0 + li;
      qg[(size_t)(rowh0 + i) * 128 + d] = f2bf(sQ[li * 132 + d] * expf(gc_s[i]));
    }
    // attn rows
    {
      int rp = tid >> 4, cg = tid & 15;
      float a_acc[2][4] = {};
      for (int d4 = 0; d4 < 128; d4 += 4) {
        float4 q0 = *(float4*)&sQ[(rp * 2 + 0) * 132 + d4];
        float4 q1 = *(float4*)&sQ[(rp * 2 + 1) * 132 + d4];
#pragma unroll
        for (int jj = 0; jj < 4; jj++) {
          float4 kv = *(float4*)&sK[(cg * 4 + jj) * 132 + d4];
          a_acc[0][jj] += q0.x * kv.x + q0.y * kv.y + q0.z * kv.z + q0.w * kv.w;
          a_acc[1][jj] += q1.x * kv.x + q1.y * kv.y + q1.z * kv.z + q1.w * kv.w;
        }
      }
#pragma unroll
      for (int rr = 0; rr < 2; rr++) {
        int i = i0 + rp * 2 + rr;
        float o[4];
#pragma unroll
        for (int jj = 0; jj < 4; jj++) {
          int j = cg * 4 + jj;
          o[jj] = (j <= i) ? a_acc[rr][jj] * expf(gc_s[i] - gc_s[j]) : 0.f;
        }
        uint2 ov;
        ov.x = pack2(o[0], o[1]);
        ov.y = pack2(o[2], o[3]);
        *(uint2*)&attn[(size_t)(bh * 64 + n) * 4096 + i * 64 + cg * 4] = ov;
      }
    }
  }

  // tri into sQ region (stride 66)
  float* tri = sQ;
  {
    int rp = tid >> 4, cg = tid & 15;
    float t_acc[4][4] = {};
    for (int d4 = 0; d4 < 128; d4 += 4) {
      float4 ka[4];
#pragma unroll
      for (int rr = 0; rr < 4; rr++) ka[rr] = *(float4*)&sK[(rp * 4 + rr) * 132 + d4];
#pragma unroll
      for (int jj = 0; jj < 4; jj++) {
        float4 kb = *(float4*)&sK[(cg * 4 + jj) * 132 + d4];
#pragma unroll
        for (int rr = 0; rr < 4; rr++)
          t_acc[rr][jj] += ka[rr].x * kb.x + ka[rr].y * kb.y + ka[rr].z * kb.z + ka[rr].w * kb.w;
      }
    }
    __syncthreads();
#pragma unroll
    for (int rr = 0; rr < 4; rr++)
#pragma unroll
      for (int jj = 0; jj < 4; jj++) {
        int i = rp * 4 + rr, j = cg * 4 + jj;
        tri[i * 66 + j] = (j < i) ? bet_s[i] * expf(gc_s[i] - gc_s[j]) * t_acc[rr][jj] : 0.f;
      }
  }
  __syncthreads();

  // forward substitution, both RHS
  {
    int mat = tid >> 7, c = tid & 127;
    float x[64];
    if (mat == 0) {
#pragma unroll
      for (int i = 0; i < 64; i++) x[i] = sK[i * 132 + c] * bet_s[i] * expf(gc_s[i]);
    } else {
      int col = 2048 + h * 128 + c;
      for (int i = 0; i < 64; i++) {
        float a = 0.f;
        int tg = t0 + i - 3;
#pragma unroll
        for (int tap = 0; tap < 4; tap++)
          if (tg + tap >= 0) a += bf2f(mixed[(size_t)(b * Tn + tg + tap) * 3072 + col]) * cw[col * 4 + tap];
        a = a / (1.f + expf(-a));
        x[i] = a * bet_s[i];
      }
    }
#pragma unroll
    for (int i = 1; i < 64; i++) {
      float s = x[i];
#pragma unroll
      for (int l = 0; l < i; l++) s -= tri[i * 66 + l] * x[l];
      x[i] = s;
    }
    if (mat == 0) {
#pragma unroll
      for (int i = 0; i < 64; i++) kcum[(size_t)(rowh0 + i) * 128 + c] = f2bf(x[i]);
    } else {
#pragma unroll
      for (int i = 0; i < 64; i++) vnew[(size_t)(rowh0 + i) * 128 + c] = f2bf(x[i]);
    }
  }
  if (tid == 0) egl[bh * 64 + n] = expf(gl);
}

// ---------------------------------------------------------------------------
// Sequential inter-chunk scan. Grid: (8 dv-tiles of 16, 16 bh). 256 threads.
// ---------------------------------------------------------------------------
__global__ __launch_bounds__(256) void scan_k(const u16* __restrict__ qg,
                                              const u16* __restrict__ kd,
                                              const u16* __restrict__ vnew,
                                              const u16* __restrict__ kcum,
                                              const u16* __restrict__ attn,
                                              const float* __restrict__ egl,
                                              float* __restrict__ core) {
  __shared__ float sStage[64 * 132];
  __shared__ float sS[128 * 20];
  __shared__ float sVn[64 * 20];
  int tile = blockIdx.x, bh = blockIdx.y;
  int dvoff = tile * 16;
  int b = bh >> 3, h = bh & 7;
  int tid = threadIdx.x;

  for (int r = tid; r < 128 * 20; r += 256) sS[r] = 0.f;
  __syncthreads();

  int i_b = tid >> 2, c0 = (tid & 3) * 4;
  int k0 = tid >> 2;

  for (int n = 0; n < 64; n++) {
    size_t chunkrow = (size_t)(bh * Tn + n * 64);
    // A: stage kcum (bf16 -> f32)
#pragma unroll
    for (int r = 0; r < 4; r++) {
      int f8i = r * 256 + tid;
      int i = f8i >> 4, d8 = (f8i & 15) * 8;
      uint4 v = *(const uint4*)&kcum[(chunkrow + i) * 128 + d8];
      float o0[8];
      o0[0] = bf2f(v.x & 0xffff); o0[1] = bf2f(v.x >> 16);
      o0[2] = bf2f(v.y & 0xffff); o0[3] = bf2f(v.y >> 16);
      o0[4] = bf2f(v.z & 0xffff); o0[5] = bf2f(v.z >> 16);
      o0[6] = bf2f(v.w & 0xffff); o0[7] = bf2f(v.w >> 16);
      *(float4*)&sStage[i * 132 + d8] = *(float4*)&o0[0];
      *(float4*)&sStage[i * 132 + d8 + 4] = *(float4*)&o0[4];
    }
    __syncthreads();
    // B: vn = vnew - kcum @ S
    uint2 vload = *(const uint2*)&vnew[(chunkrow + i_b) * 128 + dvoff + c0];
    float4 acc;
    acc.x = bf2f(vload.x & 0xffff); acc.y = bf2f(vload.x >> 16);
    acc.z = bf2f(vload.y & 0xffff); acc.w = bf2f(vload.y >> 16);
#pragma unroll 8
    for (int k = 0; k < 128; k++) {
      float kv = sStage[i_b * 132 + k];
      float4 s4 = *(float4*)&sS[k * 20 + c0];
      acc.x -= kv * s4.x; acc.y -= kv * s4.y; acc.z -= kv * s4.z; acc.w -= kv * s4.w;
    }
    *(float4*)&sVn[i_b * 20 + c0] = acc;
    __syncthreads();
    // C: stage qg
#pragma unroll
    for (int r = 0; r < 4; r++) {
      int f8i = r * 256 + tid;
      int i = f8i >> 4, d8 = (f8i & 15) * 8;
      uint4 v = *(const uint4*)&qg[(chunkrow + i) * 128 + d8];
      float o0[8];
      o0[0] = bf2f(v.x & 0xffff); o0[1] = bf2f(v.x >> 16);
      o0[2] = bf2f(v.y & 0xffff); o0[3] = bf2f(v.y >> 16);
      o0[4] = bf2f(v.z & 0xffff); o0[5] = bf2f(v.z >> 16);
      o0[6] = bf2f(v.w & 0xffff); o0[7] = bf2f(v.w >> 16);
      *(float4*)&sStage[i * 132 + d8] = *(float4*)&o0[0];
      *(float4*)&sStage[i * 132 + d8 + 4] = *(float4*)&o0[4];
    }
    __syncthreads();
    // D: out = qg @ S + attn @ vn
    float4 o = make_float4(0.f, 0.f, 0.f, 0.f);
#pragma unroll 8
    for (int k = 0; k < 128; k++) {
      float qv = sStage[i_b * 132 + k];
      float4 s4 = *(float4*)&sS[k * 20 + c0];
      o.x += qv * s4.x; o.y += qv * s4.y; o.z += qv * s4.z; o.w += qv * s4.w;
    }
    {
      const u16* arow = &attn[(size_t)(bh * 64 + n) * 4096 + i_b * 64];
#pragma unroll 4
      for (int j = 0; j < 64; j += 4) {
        uint2 a2 = *(const uint2*)&arow[j];
        float av[4];
        av[0] = bf2f(a2.x & 0xffff); av[1] = bf2f(a2.x >> 16);
        av[2] = bf2f(a2.y & 0xffff); av[3] = bf2f(a2.y >> 16);
#pragma unroll
        for (int jj = 0; jj < 4; jj++) {
          float4 v4 = *(float4*)&sVn[(j + jj) * 20 + c0];
          o.x += av[jj] * v4.x; o.y += av[jj] * v4.y; o.z += av[jj] * v4.z; o.w += av[jj] * v4.w;
        }
      }
    }
    *(float4*)&core[((size_t)(b * Tn) + n * 64 + i_b) * 1024 + h * 128 + dvoff + c0] = o;
    __syncthreads();
    // E: stage kd
#pragma unroll
    for (int r = 0; r < 4; r++) {
      int f8i = r * 256 + tid;
      int i = f8i >> 4, d8 = (f8i & 15) * 8;
      uint4 v = *(const uint4*)&kd[(chunkrow + i) * 128 + d8];
      float o0[8];
      o0[0] = bf2f(v.x & 0xffff); o0[1] = bf2f(v.x >> 16);
      o0[2] = bf2f(v.y & 0xffff); o0[3] = bf2f(v.y >> 16);
      o0[4] = bf2f(v.z & 0xffff); o0[5] = bf2f(v.z >> 16);
      o0[6] = bf2f(v.w & 0xffff); o0[7] = bf2f(v.w >> 16);
      *(float4*)&sStage[i * 132 + d8] = *(float4*)&o0[0];
      *(float4*)&sStage[i * 132 + d8 + 4] = *(float4*)&o0[4];
    }
    __syncthreads();
    // F: S = eg*S + kd^T @ vn
    {
      float eg = egl[bh * 64 + n];
      float4 sa = *(float4*)&sS[k0 * 20 + c0];
      float4 sb = *(float4*)&sS[(k0 + 64) * 20 + c0];
      sa.x *= eg; sa.y *= eg; sa.z *= eg; sa.w *= eg;
      sb.x *= eg; sb.y *= eg; sb.z *= eg; sb.w *= eg;
#pragma unroll 8
      for (int i = 0; i < 64; i++) {
        float ka = sStage[i * 132 + k0];
        float kb2 = sStage[i * 132 + k0 + 64];
        float4 v4 = *(float4*)&sVn[i * 20 + c0];
        sa.x += ka * v4.x; sa.y += ka * v4.y; sa.z += ka * v4.z; sa.w += ka * v4.w;
        sb.x += kb2 * v4.x; sb.y += kb2 * v4.y; sb.z += kb2 * v4.z; sb.w += kb2 * v4.w;
      }
      *(float4*)&sS[k0 * 20 + c0] = sa;
      *(float4*)&sS[(k0 + 64) * 20 + c0] = sb;
    }
    __syncthreads();
  }
}

// ---------------------------------------------------------------------------
// Gated RMSNorm, z from bf16.
// ---------------------------------------------------------------------------
__global__ __launch_bounds__(256) void gnorm(float* __restrict__ core,
                                             const u16* __restrict__ z,
                                             const float* __restrict__ nw) {
  __shared__ float red[256];
  __shared__ float rstd[8];
  int row = blockIdx.x, tid = threadIdx.x;
  float4 c4 = *(float4*)&core[(size_t)row * 1024 + tid * 4];
  uint2 zl = *(const uint2*)&z[(size_t)row * 1024 + tid * 4];
  float4 z4;
  z4.x = bf2f(zl.x & 0xffff); z4.y = bf2f(zl.x >> 16);
  z4.z = bf2f(zl.y & 0xffff); z4.w = bf2f(zl.y >> 16);
  red[tid] = c4.x * c4.x + c4.y * c4.y + c4.z * c4.z + c4.w * c4.w;
  __syncthreads();
  if (tid < 8) {
    float s = 0.f;
    for (int t2 = tid * 32; t2 < tid * 32 + 32; t2++) s += red[t2];
    rstd[tid] = rsqrtf(s * (1.f / 128.f) + 1e-6f);
  }
  __syncthreads();
  float rs = rstd[tid >> 5];
  int d0 = (tid * 4) & 127;
  float4 w4 = *(const float4*)&nw[d0];
  float4 o;
  o.x = c4.x * rs * w4.x * (z4.x / (1.f + expf(-z4.x)));
  o.y = c4.y * rs * w4.y * (z4.y / (1.f + expf(-z4.y)));
  o.z = c4.z * rs * w4.z * (z4.z / (1.f + expf(-z4.z)));
  o.w = c4.w * rs * w4.w * (z4.w / (1.f + expf(-z4.w)));
  *(float4*)&core[(size_t)row * 1024 + tid * 4] = o;
}

// ---------------------------------------------------------------------------
extern "C" void kernel_launch(void* const* d_in, const int* in_sizes, int n_in,
                              void* d_out, int out_size, void* d_ws, size_t ws_size,
                              hipStream_t stream) {
  const float* x     = (const float*)d_in[0];
  const float* Wqkvz = (const float*)d_in[1];
  const float* Wba   = (const float*)d_in[2];
  const float* convw = (const float*)d_in[3];
  const float* dtb   = (const float*)d_in[4];
  const float* Alog  = (const float*)d_in[5];
  const float* nw    = (const float*)d_in[6];
  const float* Wout  = (const float*)d_in[7];
  float* out = (float*)d_out;

  // Workspace layout (bytes), total 143,134,720 (~136.5 MB):
  char* w = (char*)d_ws;
  u16*   mixed = (u16*)w;                      //  50,331,648 B (bf16 2*4096*3072)
  float* core  = (float*)w;                    //  33,554,432 B — ALIASES mixed (dead after prep)
  u16*   zb    = (u16*)(w + 50331648);         //  16,777,216 B
  float* betab = (float*)(w + 67108864);       //     262,144 B
  float* gb    = (float*)(w + 67371008);       //     262,144 B
  u16*   qgB   = (u16*)(w + 67633152);         //  16,777,216 B
  u16*   kdB   = (u16*)(w + 84410368);         //  16,777,216 B
  u16*   vnB   = (u16*)(w + 101187584);        //  16,777,216 B
  u16*   kcB   = (u16*)(w + 117964800);        //  16,777,216 B
  u16*   atB   = (u16*)(w + 134742016);        //   8,388,608 B
  float* eglB  = (float*)(w + 143130624);      //       4,096 B

  gemm_qkvz<<<dim3(32, 64), 256, 0, stream>>>(x, Wqkvz, mixed, zb);
  ba_kernel<<<dim3(8192), 128, 0, stream>>>(x, Wba, dtb, Alog, betab, gb);
  prep<<<dim3(64, 16), 256, 0, stream>>>(mixed, convw, gb, betab, qgB, kdB, vnB, kcB, atB, eglB);
  scan_k<<<dim3(8, 16), 256, 0, stream>>>(qgB, kdB, vnB, kcB, atB, eglB, core);
  gnorm<<<dim3(8192), 256, 0, stream>>>(core, zb, nw);
  gemm_out<<<dim3(8, 64), 256, 0, stream>>>(core, Wout, out);
}

// Round 3
// 1307.153 us; speedup vs baseline: 1.7213x; 1.7213x over previous
//
#include <hip/hip_runtime.h>
#include <cstddef>

#define Bx 2
#define Tn 4096
#define Hh 8

typedef unsigned short u16;
typedef unsigned int u32;
typedef __attribute__((ext_vector_type(8))) short short8;
typedef __attribute__((ext_vector_type(4))) float f32x4;

__device__ __forceinline__ float bf2f(u16 u) {
  u32 x = ((u32)u) << 16;
  return __uint_as_float(x);
}
__device__ __forceinline__ u16 f2bf(float f) {
  u32 x = __float_as_uint(f);
  u32 lsb = (x >> 16) & 1;
  x += 0x7fffu + lsb;
  return (u16)(x >> 16);
}
__device__ __forceinline__ u32 pack2(float a, float b) {
  return (u32)f2bf(a) | ((u32)f2bf(b) << 16);
}
__device__ __forceinline__ void async16(u16* lds, const u16* g) {
  __builtin_amdgcn_global_load_lds((const __attribute__((address_space(1))) void*)g,
                                   (__attribute__((address_space(3))) void*)lds, 16, 0, 0);
}

// ---------------------------------------------------------------------------
// f32 -> bf16 elementwise convert (n divisible by 2048)
// ---------------------------------------------------------------------------
__global__ __launch_bounds__(256) void conv_bf16(const float* __restrict__ X,
                                                 u16* __restrict__ Xb) {
  int i = (blockIdx.x * 256 + threadIdx.x) * 8;
  float4 v0 = *(const float4*)&X[i];
  float4 v1 = *(const float4*)&X[i + 4];
  uint4 pv;
  pv.x = pack2(v0.x, v0.y);
  pv.y = pack2(v0.z, v0.w);
  pv.z = pack2(v1.x, v1.y);
  pv.w = pack2(v1.z, v1.w);
  *(uint4*)&Xb[i] = pv;
}

// ---------------------------------------------------------------------------
// Transpose-convert: W[K][N] f32 -> WT[N][K] bf16. 64x64 tiles.
// ---------------------------------------------------------------------------
__global__ __launch_bounds__(256) void transpose_bf16(const float* __restrict__ W,
                                                      u16* __restrict__ WT,
                                                      int K, int N) {
  __shared__ float tile[64][68];
  int nb = blockIdx.x, kb = blockIdx.y;
  int tid = threadIdx.x;
  int r = tid >> 4, c4 = (tid & 15) * 4;
#pragma unroll
  for (int p = 0; p < 4; p++) {
    int k = kb * 64 + p * 16 + r;
    float4 v = *(const float4*)&W[(size_t)k * N + nb * 64 + c4];
    tile[p * 16 + r][c4] = v.x;
    tile[p * 16 + r][c4 + 1] = v.y;
    tile[p * 16 + r][c4 + 2] = v.z;
    tile[p * 16 + r][c4 + 3] = v.w;
  }
  __syncthreads();
  int rn = tid >> 2, ck = (tid & 3) * 16;
#pragma unroll
  for (int s = 0; s < 2; s++) {
    int k0 = ck + s * 8;
    uint4 pv;
    pv.x = pack2(tile[k0 + 0][rn], tile[k0 + 1][rn]);
    pv.y = pack2(tile[k0 + 2][rn], tile[k0 + 3][rn]);
    pv.z = pack2(tile[k0 + 4][rn], tile[k0 + 5][rn]);
    pv.w = pack2(tile[k0 + 6][rn], tile[k0 + 7][rn]);
    *(uint4*)&WT[(size_t)(nb * 64 + rn) * K + kb * 64 + k0] = pv;
  }
}

// ---------------------------------------------------------------------------
// bf16 MFMA GEMM, both operands K-contiguous (A row-major, B^T row-major).
// 128x128 tile, BK=32, 256 thr = 4 waves, each wave 64x64 via 4x4 MFMA 16x16x32.
// K = 1024. EPI=1: qkvz split epilogue (bf16). EPI=0: fp32 plain store.
// ---------------------------------------------------------------------------
template<int EPI>
__global__ __launch_bounds__(256) void gemm_mfma(const u16* __restrict__ A,
                                                 const u16* __restrict__ Bt,
                                                 u16* __restrict__ O1,
                                                 u16* __restrict__ O2,
                                                 float* __restrict__ O3,
                                                 int Nfull) {
  const int K = 1024;
  __shared__ u16 As[128 * 32];
  __shared__ u16 Bs[128 * 32];
  int bn = blockIdx.x, bm = blockIdx.y;
  int tid = threadIdx.x;
  int wave = tid >> 6, lane = tid & 63;
  int wr = wave >> 1, wc = wave & 1;

  f32x4 acc[4][4];
#pragma unroll
  for (int i = 0; i < 4; i++)
#pragma unroll
    for (int j = 0; j < 4; j++) acc[i][j] = (f32x4){0.f, 0.f, 0.f, 0.f};

  // staging: wave stages A rows wave*32..+31 and B^T rows wave*32..+31
  const u16* Ab = A + (size_t)(bm * 128 + wave * 32 + (lane >> 2)) * K + (lane & 3) * 8;
  const u16* Bb = Bt + (size_t)(bn * 128 + wave * 32 + (lane >> 2)) * K + (lane & 3) * 8;
  u16* AsW = &As[(wave * 32) * 32];
  u16* BsW = &Bs[(wave * 32) * 32];

  int m_lane = lane & 15, k_lane = (lane >> 4) * 8;
  const u16* arow0 = &As[(wr * 64 + m_lane) * 32 + k_lane];
  const u16* brow0 = &Bs[(wc * 64 + m_lane) * 32 + k_lane];

  for (int kk = 0; kk < K; kk += 32) {
    __syncthreads();
    async16(AsW, Ab + kk);
    async16(AsW + 16 * 32, Ab + 16 * K + kk);
    async16(BsW, Bb + kk);
    async16(BsW + 16 * 32, Bb + 16 * K + kk);
    __syncthreads();
    short8 a[4], b[4];
#pragma unroll
    for (int t = 0; t < 4; t++) a[t] = *(const short8*)(arow0 + t * 16 * 32);
#pragma unroll
    for (int t = 0; t < 4; t++) b[t] = *(const short8*)(brow0 + t * 16 * 32);
#pragma unroll
    for (int i = 0; i < 4; i++)
#pragma unroll
      for (int j = 0; j < 4; j++)
        acc[i][j] = __builtin_amdgcn_mfma_f32_16x16x32_bf16(a[i], b[j], acc[i][j], 0, 0, 0);
  }

  // epilogue: C/D layout col=lane&15, row=(lane>>4)*4+reg
  int n0 = bn * 128;
  int cbase = wc * 64 + (lane & 15);
  int rbase = bm * 128 + wr * 64 + ((lane >> 4) * 4);
  if (EPI == 1) {
    int h = n0 >> 9, sub = (n0 >> 7) & 3;
    u16* dst;
    size_t stride;
    if (sub < 3) { dst = O1 + (size_t)(sub * 1024 + h * 128); stride = 3072; }
    else         { dst = O2 + (size_t)(h * 128);              stride = 1024; }
#pragma unroll
    for (int i = 0; i < 4; i++)
#pragma unroll
      for (int j = 0; j < 4; j++)
#pragma unroll
        for (int r = 0; r < 4; r++)
          dst[(size_t)(rbase + i * 16 + r) * stride + cbase + j * 16] = f2bf(acc[i][j][r]);
  } else {
#pragma unroll
    for (int i = 0; i < 4; i++)
#pragma unroll
      for (int j = 0; j < 4; j++)
#pragma unroll
        for (int r = 0; r < 4; r++)
          O3[(size_t)(rbase + i * 16 + r) * Nfull + n0 + cbase + j * 16] = acc[i][j][r];
  }
}

// ---------------------------------------------------------------------------
// ba = x @ W_ba then beta = sigmoid(b), g = -exp(A)*softplus(a+dt)
// ---------------------------------------------------------------------------
__global__ __launch_bounds__(128) void ba_kernel(const float* __restrict__ x,
                                                 const float* __restrict__ Wba,
                                                 const float* __restrict__ dtb,
                                                 const float* __restrict__ Alog,
                                                 float* __restrict__ betab,
                                                 float* __restrict__ gb) {
  __shared__ float xs[1024];
  __shared__ float part[8][16];
  int row = blockIdx.x, tid = threadIdx.x;
#pragma unroll
  for (int r = 0; r < 2; r++) {
    int f4 = r * 128 + tid;
    *(float4*)&xs[f4 * 4] = *(const float4*)&x[(size_t)row * 1024 + f4 * 4];
  }
  __syncthreads();
  int col = tid & 15, seg = tid >> 4;
  float a = 0.f;
  for (int k = seg * 128; k < seg * 128 + 128; k++) a += xs[k] * Wba[k * 16 + col];
  part[seg][col] = a;
  __syncthreads();
  if (tid < 8) {
    float bval = 0.f, aval = 0.f;
#pragma unroll
    for (int q = 0; q < 8; q++) { bval += part[q][tid * 2]; aval += part[q][tid * 2 + 1]; }
    betab[(size_t)row * 8 + tid] = 1.f / (1.f + expf(-bval));
    float spin = aval + dtb[tid];
    float sp = (spin > 20.f) ? spin : log1pf(expf(spin));
    gb[(size_t)row * 8 + tid] = -expf(Alog[tid]) * sp;
  }
}

// ---------------------------------------------------------------------------
// Per-chunk prep. One block per (chunk, bh). 256 threads.
// ---------------------------------------------------------------------------
__global__ __launch_bounds__(256) void prep(const u16* __restrict__ mixed,
                                            const float* __restrict__ cw,
                                            const float* __restrict__ gbuf,
                                            const float* __restrict__ betabuf,
                                            u16* __restrict__ qg,
                                            u16* __restrict__ kd,
                                            u16* __restrict__ vnew,
                                            u16* __restrict__ kcum,
                                            u16* __restrict__ attn,
                                            float* __restrict__ egl) {
  __shared__ float sK[64 * 132];
  __shared__ float sQ[32 * 132];  // reused as tri[64*66]
  __shared__ float gc_s[64], bet_s[64], inv_s[64], red_s[256];

  int n = blockIdx.x, bh = blockIdx.y;
  int b = bh >> 3, h = bh & 7;
  int t0 = n * 64;
  int tid = threadIdx.x;
  const int rowg0 = b * Tn + t0;
  const int rowh0 = bh * Tn + t0;

  if (tid < 64) {
    red_s[tid] = gbuf[(size_t)(rowg0 + tid) * 8 + h];
    bet_s[tid] = betabuf[(size_t)(rowg0 + tid) * 8 + h];
  }
  __syncthreads();
  if (tid == 0) {
    float s = 0.f;
    for (int i = 0; i < 64; i++) { s += red_s[i]; gc_s[i] = s; }
  }
  __syncthreads();
  float gl = gc_s[63];

  // conv k -> sK, silu
  for (int r = 0; r < 32; r++) {
    int idx = r * 256 + tid;
    int i = idx >> 7, d = idx & 127;
    int col = 1024 + h * 128 + d;
    float a = 0.f;
    int tg = t0 + i - 3;
#pragma unroll
    for (int tap = 0; tap < 4; tap++)
      if (tg + tap >= 0) a += bf2f(mixed[(size_t)(b * Tn + tg + tap) * 3072 + col]) * cw[col * 4 + tap];
    a = a / (1.f + expf(-a));
    sK[i * 132 + d] = a;
  }
  __syncthreads();
  {
    int i = tid >> 2, p = tid & 3;
    float ss = 0.f;
    for (int d = p * 32; d < p * 32 + 32; d++) { float v = sK[i * 132 + d]; ss += v * v; }
    red_s[tid] = ss;
  }
  __syncthreads();
  if (tid < 64)
    inv_s[tid] = rsqrtf(red_s[tid * 4] + red_s[tid * 4 + 1] + red_s[tid * 4 + 2] + red_s[tid * 4 + 3] + 1e-6f);
  __syncthreads();
  for (int r = 0; r < 32; r++) {
    int idx = r * 256 + tid;
    int i = idx >> 7, d = idx & 127;
    sK[i * 132 + d] *= inv_s[i];
  }
  __syncthreads();
  for (int r = 0; r < 32; r++) {
    int idx = r * 256 + tid;
    int i = idx >> 7, d = idx & 127;
    kd[(size_t)(rowh0 + i) * 128 + d] = f2bf(sK[i * 132 + d] * expf(gl - gc_s[i]));
  }

  // q halves
  for (int half = 0; half < 2; half++) {
    int i0 = half * 32;
    __syncthreads();
    for (int r = 0; r < 16; r++) {
      int idx = r * 256 + tid;
      int li = idx >> 7, d = idx & 127;
      int i = i0 + li;
      int col = h * 128 + d;
      float a = 0.f;
      int tg = t0 + i - 3;
#pragma unroll
      for (int tap = 0; tap < 4; tap++)
        if (tg + tap >= 0) a += bf2f(mixed[(size_t)(b * Tn + tg + tap) * 3072 + col]) * cw[col * 4 + tap];
      a = a / (1.f + expf(-a));
      sQ[li * 132 + d] = a;
    }
    __syncthreads();
    if (tid < 128) {
      int li = tid >> 2, p = tid & 3;
      float ss = 0.f;
      for (int d = p * 32; d < p * 32 + 32; d++) { float v = sQ[li * 132 + d]; ss += v * v; }
      red_s[tid] = ss;
    }
    __syncthreads();
    if (tid < 32)
      inv_s[tid] = rsqrtf(red_s[tid * 4] + red_s[tid * 4 + 1] + red_s[tid * 4 + 2] + red_s[tid * 4 + 3] + 1e-6f) *
                   0.08838834764831845f;
    __syncthreads();
    for (int r = 0; r < 16; r++) {
      int idx = r * 256 + tid;
      int li = idx >> 7, d = idx & 127;
      sQ[li * 132 + d] *= inv_s[li];
    }
    __syncthreads();
    for (int r = 0; r < 16; r++) {
      int idx = r * 256 + tid;
      int li = idx >> 7, d = idx & 127;
      int i = i0 + li;
      qg[(size_t)(rowh0 + i) * 128 + d] = f2bf(sQ[li * 132 + d] * expf(gc_s[i]));
    }
    // attn rows
    {
      int rp = tid >> 4, cg = tid & 15;
      float a_acc[2][4] = {};
      for (int d4 = 0; d4 < 128; d4 += 4) {
        float4 q0 = *(float4*)&sQ[(rp * 2 + 0) * 132 + d4];
        float4 q1 = *(float4*)&sQ[(rp * 2 + 1) * 132 + d4];
#pragma unroll
        for (int jj = 0; jj < 4; jj++) {
          float4 kv = *(float4*)&sK[(cg * 4 + jj) * 132 + d4];
          a_acc[0][jj] += q0.x * kv.x + q0.y * kv.y + q0.z * kv.z + q0.w * kv.w;
          a_acc[1][jj] += q1.x * kv.x + q1.y * kv.y + q1.z * kv.z + q1.w * kv.w;
        }
      }
#pragma unroll
      for (int rr = 0; rr < 2; rr++) {
        int i = i0 + rp * 2 + rr;
        float o[4];
#pragma unroll
        for (int jj = 0; jj < 4; jj++) {
          int j = cg * 4 + jj;
          o[jj] = (j <= i) ? a_acc[rr][jj] * expf(gc_s[i] - gc_s[j]) : 0.f;
        }
        uint2 ov;
        ov.x = pack2(o[0], o[1]);
        ov.y = pack2(o[2], o[3]);
        *(uint2*)&attn[(size_t)(bh * 64 + n) * 4096 + i * 64 + cg * 4] = ov;
      }
    }
  }

  // tri into sQ region (stride 66)
  float* tri = sQ;
  {
    int rp = tid >> 4, cg = tid & 15;
    float t_acc[4][4] = {};
    for (int d4 = 0; d4 < 128; d4 += 4) {
      float4 ka[4];
#pragma unroll
      for (int rr = 0; rr < 4; rr++) ka[rr] = *(float4*)&sK[(rp * 4 + rr) * 132 + d4];
#pragma unroll
      for (int jj = 0; jj < 4; jj++) {
        float4 kb = *(float4*)&sK[(cg * 4 + jj) * 132 + d4];
#pragma unroll
        for (int rr = 0; rr < 4; rr++)
          t_acc[rr][jj] += ka[rr].x * kb.x + ka[rr].y * kb.y + ka[rr].z * kb.z + ka[rr].w * kb.w;
      }
    }
    __syncthreads();
#pragma unroll
    for (int rr = 0; rr < 4; rr++)
#pragma unroll
      for (int jj = 0; jj < 4; jj++) {
        int i = rp * 4 + rr, j = cg * 4 + jj;
        tri[i * 66 + j] = (j < i) ? bet_s[i] * expf(gc_s[i] - gc_s[j]) * t_acc[rr][jj] : 0.f;
      }
  }
  __syncthreads();

  // forward substitution, both RHS
  {
    int mat = tid >> 7, c = tid & 127;
    float x[64];
    if (mat == 0) {
#pragma unroll
      for (int i = 0; i < 64; i++) x[i] = sK[i * 132 + c] * bet_s[i] * expf(gc_s[i]);
    } else {
      int col = 2048 + h * 128 + c;
      for (int i = 0; i < 64; i++) {
        float a = 0.f;
        int tg = t0 + i - 3;
#pragma unroll
        for (int tap = 0; tap < 4; tap++)
          if (tg + tap >= 0) a += bf2f(mixed[(size_t)(b * Tn + tg + tap) * 3072 + col]) * cw[col * 4 + tap];
        a = a / (1.f + expf(-a));
        x[i] = a * bet_s[i];
      }
    }
#pragma unroll
    for (int i = 1; i < 64; i++) {
      float s = x[i];
#pragma unroll
      for (int l = 0; l < i; l++) s -= tri[i * 66 + l] * x[l];
      x[i] = s;
    }
    if (mat == 0) {
#pragma unroll
      for (int i = 0; i < 64; i++) kcum[(size_t)(rowh0 + i) * 128 + c] = f2bf(x[i]);
    } else {
#pragma unroll
      for (int i = 0; i < 64; i++) vnew[(size_t)(rowh0 + i) * 128 + c] = f2bf(x[i]);
    }
  }
  if (tid == 0) egl[bh * 64 + n] = expf(gl);
}

// ---------------------------------------------------------------------------
// Sequential inter-chunk scan. Grid: (8 dv-tiles of 16, 16 bh). 256 threads.
// ---------------------------------------------------------------------------
__global__ __launch_bounds__(256) void scan_k(const u16* __restrict__ qg,
                                              const u16* __restrict__ kd,
                                              const u16* __restrict__ vnew,
                                              const u16* __restrict__ kcum,
                                              const u16* __restrict__ attn,
                                              const float* __restrict__ egl,
                                              float* __restrict__ core) {
  __shared__ float sStage[64 * 132];
  __shared__ float sS[128 * 20];
  __shared__ float sVn[64 * 20];
  int tile = blockIdx.x, bh = blockIdx.y;
  int dvoff = tile * 16;
  int b = bh >> 3, h = bh & 7;
  int tid = threadIdx.x;

  for (int r = tid; r < 128 * 20; r += 256) sS[r] = 0.f;
  __syncthreads();

  int i_b = tid >> 2, c0 = (tid & 3) * 4;
  int k0 = tid >> 2;

  for (int n = 0; n < 64; n++) {
    size_t chunkrow = (size_t)(bh * Tn + n * 64);
#pragma unroll
    for (int r = 0; r < 4; r++) {
      int f8i = r * 256 + tid;
      int i = f8i >> 4, d8 = (f8i & 15) * 8;
      uint4 v = *(const uint4*)&kcum[(chunkrow + i) * 128 + d8];
      float o0[8];
      o0[0] = bf2f(v.x & 0xffff); o0[1] = bf2f(v.x >> 16);
      o0[2] = bf2f(v.y & 0xffff); o0[3] = bf2f(v.y >> 16);
      o0[4] = bf2f(v.z & 0xffff); o0[5] = bf2f(v.z >> 16);
      o0[6] = bf2f(v.w & 0xffff); o0[7] = bf2f(v.w >> 16);
      *(float4*)&sStage[i * 132 + d8] = *(float4*)&o0[0];
      *(float4*)&sStage[i * 132 + d8 + 4] = *(float4*)&o0[4];
    }
    __syncthreads();
    uint2 vload = *(const uint2*)&vnew[(chunkrow + i_b) * 128 + dvoff + c0];
    float4 acc;
    acc.x = bf2f(vload.x & 0xffff); acc.y = bf2f(vload.x >> 16);
    acc.z = bf2f(vload.y & 0xffff); acc.w = bf2f(vload.y >> 16);
#pragma unroll 8
    for (int k = 0; k < 128; k++) {
      float kv = sStage[i_b * 132 + k];
      float4 s4 = *(float4*)&sS[k * 20 + c0];
      acc.x -= kv * s4.x; acc.y -= kv * s4.y; acc.z -= kv * s4.z; acc.w -= kv * s4.w;
    }
    *(float4*)&sVn[i_b * 20 + c0] = acc;
    __syncthreads();
#pragma unroll
    for (int r = 0; r < 4; r++) {
      int f8i = r * 256 + tid;
      int i = f8i >> 4, d8 = (f8i & 15) * 8;
      uint4 v = *(const uint4*)&qg[(chunkrow + i) * 128 + d8];
      float o0[8];
      o0[0] = bf2f(v.x & 0xffff); o0[1] = bf2f(v.x >> 16);
      o0[2] = bf2f(v.y & 0xffff); o0[3] = bf2f(v.y >> 16);
      o0[4] = bf2f(v.z & 0xffff); o0[5] = bf2f(v.z >> 16);
      o0[6] = bf2f(v.w & 0xffff); o0[7] = bf2f(v.w >> 16);
      *(float4*)&sStage[i * 132 + d8] = *(float4*)&o0[0];
      *(float4*)&sStage[i * 132 + d8 + 4] = *(float4*)&o0[4];
    }
    __syncthreads();
    float4 o = make_float4(0.f, 0.f, 0.f, 0.f);
#pragma unroll 8
    for (int k = 0; k < 128; k++) {
      float qv = sStage[i_b * 132 + k];
      float4 s4 = *(float4*)&sS[k * 20 + c0];
      o.x += qv * s4.x; o.y += qv * s4.y; o.z += qv * s4.z; o.w += qv * s4.w;
    }
    {
      const u16* arow = &attn[(size_t)(bh * 64 + n) * 4096 + i_b * 64];
#pragma unroll 4
      for (int j = 0; j < 64; j += 4) {
        uint2 a2 = *(const uint2*)&arow[j];
        float av[4];
        av[0] = bf2f(a2.x & 0xffff); av[1] = bf2f(a2.x >> 16);
        av[2] = bf2f(a2.y & 0xffff); av[3] = bf2f(a2.y >> 16);
#pragma unroll
        for (int jj = 0; jj < 4; jj++) {
          float4 v4 = *(float4*)&sVn[(j + jj) * 20 + c0];
          o.x += av[jj] * v4.x; o.y += av[jj] * v4.y; o.z += av[jj] * v4.z; o.w += av[jj] * v4.w;
        }
      }
    }
    *(float4*)&core[((size_t)(b * Tn) + n * 64 + i_b) * 1024 + h * 128 + dvoff + c0] = o;
    __syncthreads();
#pragma unroll
    for (int r = 0; r < 4; r++) {
      int f8i = r * 256 + tid;
      int i = f8i >> 4, d8 = (f8i & 15) * 8;
      uint4 v = *(const uint4*)&kd[(chunkrow + i) * 128 + d8];
      float o0[8];
      o0[0] = bf2f(v.x & 0xffff); o0[1] = bf2f(v.x >> 16);
      o0[2] = bf2f(v.y & 0xffff); o0[3] = bf2f(v.y >> 16);
      o0[4] = bf2f(v.z & 0xffff); o0[5] = bf2f(v.z >> 16);
      o0[6] = bf2f(v.w & 0xffff); o0[7] = bf2f(v.w >> 16);
      *(float4*)&sStage[i * 132 + d8] = *(float4*)&o0[0];
      *(float4*)&sStage[i * 132 + d8 + 4] = *(float4*)&o0[4];
    }
    __syncthreads();
    {
      float eg = egl[bh * 64 + n];
      float4 sa = *(float4*)&sS[k0 * 20 + c0];
      float4 sb = *(float4*)&sS[(k0 + 64) * 20 + c0];
      sa.x *= eg; sa.y *= eg; sa.z *= eg; sa.w *= eg;
      sb.x *= eg; sb.y *= eg; sb.z *= eg; sb.w *= eg;
#pragma unroll 8
      for (int i = 0; i < 64; i++) {
        float ka = sStage[i * 132 + k0];
        float kb2 = sStage[i * 132 + k0 + 64];
        float4 v4 = *(float4*)&sVn[i * 20 + c0];
        sa.x += ka * v4.x; sa.y += ka * v4.y; sa.z += ka * v4.z; sa.w += ka * v4.w;
        sb.x += kb2 * v4.x; sb.y += kb2 * v4.y; sb.z += kb2 * v4.z; sb.w += kb2 * v4.w;
      }
      *(float4*)&sS[k0 * 20 + c0] = sa;
      *(float4*)&sS[(k0 + 64) * 20 + c0] = sb;
    }
    __syncthreads();
  }
}

// ---------------------------------------------------------------------------
// Gated RMSNorm; writes bf16 coreb (A-operand of out GEMM).
// ---------------------------------------------------------------------------
__global__ __launch_bounds__(256) void gnorm(const float* __restrict__ core,
                                             const u16* __restrict__ z,
                                             const float* __restrict__ nw,
                                             u16* __restrict__ coreb) {
  __shared__ float red[256];
  __shared__ float rstd[8];
  int row = blockIdx.x, tid = threadIdx.x;
  float4 c4 = *(const float4*)&core[(size_t)row * 1024 + tid * 4];
  uint2 zl = *(const uint2*)&z[(size_t)row * 1024 + tid * 4];
  float4 z4;
  z4.x = bf2f(zl.x & 0xffff); z4.y = bf2f(zl.x >> 16);
  z4.z = bf2f(zl.y & 0xffff); z4.w = bf2f(zl.y >> 16);
  red[tid] = c4.x * c4.x + c4.y * c4.y + c4.z * c4.z + c4.w * c4.w;
  __syncthreads();
  if (tid < 8) {
    float s = 0.f;
    for (int t2 = tid * 32; t2 < tid * 32 + 32; t2++) s += red[t2];
    rstd[tid] = rsqrtf(s * (1.f / 128.f) + 1e-6f);
  }
  __syncthreads();
  float rs = rstd[tid >> 5];
  int d0 = (tid * 4) & 127;
  float4 w4 = *(const float4*)&nw[d0];
  float4 o;
  o.x = c4.x * rs * w4.x * (z4.x / (1.f + expf(-z4.x)));
  o.y = c4.y * rs * w4.y * (z4.y / (1.f + expf(-z4.y)));
  o.z = c4.z * rs * w4.z * (z4.z / (1.f + expf(-z4.z)));
  o.w = c4.w * rs * w4.w * (z4.w / (1.f + expf(-z4.w)));
  uint2 pv;
  pv.x = pack2(o.x, o.y);
  pv.y = pack2(o.z, o.w);
  *(uint2*)&coreb[(size_t)row * 1024 + tid * 4] = pv;
}

// ---------------------------------------------------------------------------
extern "C" void kernel_launch(void* const* d_in, const int* in_sizes, int n_in,
                              void* d_out, int out_size, void* d_ws, size_t ws_size,
                              hipStream_t stream) {
  const float* x     = (const float*)d_in[0];
  const float* Wqkvz = (const float*)d_in[1];
  const float* Wba   = (const float*)d_in[2];
  const float* convw = (const float*)d_in[3];
  const float* dtb   = (const float*)d_in[4];
  const float* Alog  = (const float*)d_in[5];
  const float* nw    = (const float*)d_in[6];
  const float* Wout  = (const float*)d_in[7];
  float* out = (float*)d_out;

  // Workspace layout, total 143,134,720 B (proven size). Aliases are
  // lifetime-disjoint in stream order:
  //   mixed [gemm..prep]  |  core f32 [scan..gnorm] (w+0, 32MB)
  //   coreb bf16 [gnorm..gemm_out] at w+32MB (tail of mixed region)
  //   xb  [conv..gemm_qkvz]  aliases qgB  (qg live prep..scan)
  //   WqT [conv..gemm_qkvz]  aliases kdB
  //   WoT [post-scan..gemm_out] aliases kcB (kc dead after scan)
  char* w = (char*)d_ws;
  u16*   mixed = (u16*)w;                      // 50,331,648 B
  float* core  = (float*)w;                    // 33,554,432 B
  u16*   coreb = (u16*)(w + 33554432);         // 16,777,216 B
  u16*   zb    = (u16*)(w + 50331648);         // 16,777,216 B
  float* betab = (float*)(w + 67108864);       //    262,144 B
  float* gb    = (float*)(w + 67371008);       //    262,144 B
  u16*   qgB   = (u16*)(w + 67633152);         // 16,777,216 B
  u16*   xb    = (u16*)(w + 67633152);         // 16,777,216 B (alias)
  u16*   kdB   = (u16*)(w + 84410368);         // 16,777,216 B
  u16*   WqT   = (u16*)(w + 84410368);         //  8,388,608 B (alias)
  u16*   vnB   = (u16*)(w + 101187584);        // 16,777,216 B
  u16*   kcB   = (u16*)(w + 117964800);        // 16,777,216 B
  u16*   WoT   = (u16*)(w + 117964800);        //  2,097,152 B (alias)
  u16*   atB   = (u16*)(w + 134742016);        //  8,388,608 B
  float* eglB  = (float*)(w + 143130624);      //      4,096 B

  // convert inputs for MFMA
  conv_bf16<<<dim3(4096), 256, 0, stream>>>(x, xb);                    // 8192x1024
  transpose_bf16<<<dim3(64, 16), 256, 0, stream>>>(Wqkvz, WqT, 1024, 4096);
  // big GEMMs + pipeline
  gemm_mfma<1><<<dim3(32, 64), 256, 0, stream>>>(xb, WqT, mixed, zb, nullptr, 4096);
  ba_kernel<<<dim3(8192), 128, 0, stream>>>(x, Wba, dtb, Alog, betab, gb);
  prep<<<dim3(64, 16), 256, 0, stream>>>(mixed, convw, gb, betab, qgB, kdB, vnB, kcB, atB, eglB);
  scan_k<<<dim3(8, 16), 256, 0, stream>>>(qgB, kdB, vnB, kcB, atB, eglB, core);
  transpose_bf16<<<dim3(16, 16), 256, 0, stream>>>(Wout, WoT, 1024, 1024); // kc dead now
  gnorm<<<dim3(8192), 256, 0, stream>>>(core, zb, nw, coreb);
  gemm_mfma<0><<<dim3(8, 64), 256, 0, stream>>>(coreb, WoT, nullptr, nullptr, out, 1024);
}